// Round 17
// baseline (107.965 us; speedup 1.0000x reference)
//
#include <hip/hip_runtime.h>
#include <math.h>

#define SS 2048
#define QP 72   // f16 pitch sQ (48 rows/head)
#define KP 72   // f16 pitch sK (80 rows/head)
#define VP 72   // f16 pitch sVt (64 d-rows/head)
#define SFP 88  // f16 pitch sSf (48 rows/head, 80 cols used)
#define PP 72   // f16 pitch sP (32 q-rows/head, 64 key cols)

typedef __attribute__((ext_vector_type(8))) _Float16 h8v;
typedef __attribute__((ext_vector_type(2))) __fp16 p2v;
typedef __attribute__((ext_vector_type(4))) float f4v;

__device__ __forceinline__ unsigned long long pack4h(float4 v) {
    union { p2v h[2]; unsigned long long u; } t;
    t.h[0] = __builtin_amdgcn_cvt_pkrtz(v.x, v.y);
    t.h[1] = __builtin_amdgcn_cvt_pkrtz(v.z, v.w);
    return t.u;
}

__global__ __launch_bounds__(768, 3)
void mta_v17(const float* __restrict__ Q, const float* __restrict__ K,
             const float* __restrict__ V, const float* __restrict__ CW,
             const float* __restrict__ CB, const float* __restrict__ MIX,
             const float* __restrict__ GAM, const float* __restrict__ BET,
             float* __restrict__ OUT)
{
    __shared__ __align__(16) _Float16 sQ[96 * QP];       // 13824 B
    __shared__ __align__(16) _Float16 sK[2][160 * KP];   // 2 x 23040 B
    __shared__ __align__(16) _Float16 sVt[2][128 * VP];  // 2 x 18432 B
    __shared__ __align__(16) _Float16 sSf[96 * SFP];     // 16896 B
    __shared__ __align__(16) _Float16 sP[64 * PP];       // 9216 B
    __shared__ float sResc[2][32];
    __shared__ float sL[2][32];
    __shared__ float sW2[2][66];
    __shared__ float sB2[2];
    // ~121 KB -> hardware-guaranteed 1 block/CU; 12 waves = 3 waves/SIMD

    const int tid = threadIdx.x;
    const int g = blockIdx.x & 7;
    const int u = blockIdx.x >> 3;   // 0..31

    const int wv = tid >> 6, lane = tid & 63;
    const int lrow = lane & 15;            // MFMA A/B row, C col
    const int lk8 = (lane >> 4) << 3;      // MFMA contraction offset
    const int crow4 = (lane >> 4) << 2;    // MFMA C row base

    const bool isConv = (wv >= 8);
    // conv wave role (waves 8-11): (head, m-tile)
    const int cwv = wv - 8;
    const int hC = (cwv >> 1) & 1, mtw = cwv & 1;
    // stage/PV wave role (waves 0-7): (i = src head, j = dst head, nh = d-half)
    const int i_pv = (wv >> 2) & 1, j_pv = (wv >> 1) & 1, nh = wv & 1;

    for (int idx = tid; idx < 132; idx += 768) {
        int h = idx >= 66;
        sW2[h][idx - (h ? 66 : 0)] = CW[(2 * g + h) * 66 + (idx - (h ? 66 : 0))];
    }
    if (tid < 2) sB2[tid] = CB[2 * g + tid];
    const float mixc = MIX[g * 4 + i_pv * 2 + j_pv];
    __syncthreads();

    // ---- T fragments in registers (waves 8-11): tf_i[m=lrow][z=lk8+e] = w[i][z-m] ----
    h8v tf[6];
    float biasC = 0.f;
    if (isConv) {
        biasC = sB2[hC];
#pragma unroll
        for (int i = 0; i < 6; ++i)
#pragma unroll
            for (int e = 0; e < 8; ++e) {
                int d = lk8 + e - lrow;
                tf[i][e] = (d >= 0 && d <= 10) ? (_Float16)sW2[hC][i * 11 + d] : (_Float16)0.f;
            }
    }

    const float4* Q4 = (const float4*)Q;
    const float4* K4 = (const float4*)K;
    const float4* V4 = (const float4*)V;

    for (int ti = 0; ti < 2; ++ti) {
        const int tile = ti ? u : (63 - u);   // per-block iteration total constant (33)
        const int q0 = tile << 5;
        __syncthreads(); // P0: prev-ti consumers done before restaging

        // ---- stage extended Q tile (rows q0-2 .. q0+45), f16 ----
        for (int idx = tid; idx < 1536; idx += 768) {
            int h = idx >= 768;
            int rem = idx - (h ? 768 : 0);
            int e = rem >> 4, d4 = rem & 15;
            int r = q0 - 2 + e;
            float4 val = make_float4(0.f, 0.f, 0.f, 0.f);
            if (r >= 0 && r < SS) val = Q4[((2 * g + h) * SS + r) * 16 + d4];
            *(unsigned long long*)&sQ[(h * 48 + e) * QP + (d4 << 2)] = pack4h(val);
        }
        // ---- direct-stage K/V buffer 0 (k0 = 0) ----
        for (int idx = tid; idx < 2560; idx += 768) {
            int h = idx >= 1280;
            int rem = idx - (h ? 1280 : 0);
            int e = rem >> 4, d4 = rem & 15;
            int c = -5 + e;
            float4 val = make_float4(0.f, 0.f, 0.f, 0.f);
            if (e < 74 && c >= 0 && c < SS) val = K4[((2 * g + h) * SS + c) * 16 + d4];
            *(unsigned long long*)&sK[0][(h * 80 + e) * KP + (d4 << 2)] = pack4h(val);
        }
        for (int idx = tid; idx < 2048; idx += 768) {
            int h = idx >> 10, d4 = (idx >> 6) & 15, kk = idx & 63;
            float4 val = V4[((2 * g + h) * SS + kk) * 16 + d4];
            int d = d4 << 2;
            sVt[0][(h * 64 + d + 0) * VP + kk] = (_Float16)val.x;
            sVt[0][(h * 64 + d + 1) * VP + kk] = (_Float16)val.y;
            sVt[0][(h * 64 + d + 2) * VP + kk] = (_Float16)val.z;
            sVt[0][(h * 64 + d + 3) * VP + kk] = (_Float16)val.w;
        }

        f4v acc[2][2];
#pragma unroll
        for (int mt = 0; mt < 2; ++mt)
#pragma unroll
            for (int n2 = 0; n2 < 2; ++n2) acc[mt][n2] = f4v{0.f, 0.f, 0.f, 0.f};
        float m_run = -INFINITY, l_run = 0.f;
        int cur = 0;

        __syncthreads(); // P1: buffer 0 + Q staged

        const int iters = (tile >> 1) + 1;   // 64 keys per iteration
        for (int it = 0; it < iters; ++it) {
            const int k0 = it << 6;
            const bool pf = (it + 1) < iters;
            const int k0n = (it + 1) << 6;
            const int nxt = cur ^ 1;

            // ---- (B) scores: 30 jobs over 12 waves, K=64, masked f16 out ----
#pragma unroll
            for (int jj = 0; jj < 3; ++jj) {
                int job = wv + jj * 12;
                if (job < 30) {
                    int h = job >= 15;
                    int r15 = job - (h ? 15 : 0);
                    int mt = (r15 >= 10) ? 2 : ((r15 >= 5) ? 1 : 0);
                    int nt = r15 - 5 * mt;
                    const _Float16* ap = &sQ[(h * 48 + mt * 16 + lrow) * QP + lk8];
                    const _Float16* bp = &sK[cur][(h * 80 + nt * 16 + lrow) * KP + lk8];
                    f4v c = f4v{0.f, 0.f, 0.f, 0.f};
                    c = __builtin_amdgcn_mfma_f32_16x16x32_f16(*(const h8v*)ap,
                                                               *(const h8v*)bp, c, 0, 0, 0);
                    c = __builtin_amdgcn_mfma_f32_16x16x32_f16(*(const h8v*)(ap + 32),
                                                               *(const h8v*)(bp + 32), c, 0, 0, 0);
                    int col = nt * 16 + lrow;
                    int cab = k0 - 5 + col;
                    int rbase = mt * 16 + crow4;
#pragma unroll
                    for (int r = 0; r < 4; ++r)
                        sSf[(h * 48 + rbase + r) * SFP + col] =
                            (_Float16)((cab <= q0 - 2 + rbase + r) ? c[r] * 0.125f : 0.f);
                }
            }
            __syncthreads(); // X: sSf published; prev PV done with sP/sResc

            // ---- (C) split: waves 8-11 transposed-conv+softmax; waves 0-7 K/V prefetch ----
            if (isConv) {
                f4v cc[4];
                __builtin_amdgcn_s_setprio(1);
#pragma unroll
                for (int ct = 0; ct < 4; ++ct) {
                    f4v c = f4v{biasC, biasC, biasC, biasC};
#pragma unroll
                    for (int i = 0; i < 6; ++i) {
                        h8v b = *(const h8v*)&sSf[(hC * 48 + mtw * 16 + i + lrow) * SFP + ct * 16 + lk8];
                        c = __builtin_amdgcn_mfma_f32_16x16x32_f16(tf[i], b, c, 0, 0, 0);
                    }
                    cc[ct] = c;
                }
                __builtin_amdgcn_s_setprio(0);
                const int qrow = q0 + mtw * 16 + lrow;
                float tm = -INFINITY;
#pragma unroll
                for (int ct = 0; ct < 4; ++ct)
#pragma unroll
                    for (int r = 0; r < 4; ++r) {
                        int ca = k0 + ct * 16 + crow4 + r;
                        float v = cc[ct][r];
                        if (ca > qrow) v = -1e9f;
                        cc[ct][r] = v;
                        tm = fmaxf(tm, v);
                    }
                tm = fmaxf(tm, __shfl_xor(tm, 16));
                tm = fmaxf(tm, __shfl_xor(tm, 32));
                float mnew = fmaxf(m_run, tm);
                float resc = __expf(m_run - mnew); // first iter: exp(-inf)=0
                m_run = mnew;
                float ps = 0.f;
#pragma unroll
                for (int ct = 0; ct < 4; ++ct)
#pragma unroll
                    for (int r = 0; r < 4; ++r) {
                        float p = __expf(cc[ct][r] - mnew);
                        cc[ct][r] = p;
                        ps += p;
                    }
                ps += __shfl_xor(ps, 16);
                ps += __shfl_xor(ps, 32);
                l_run = l_run * resc + ps;
                if ((lane >> 4) == 0) sResc[hC][mtw * 16 + lrow] = resc;
                // P write: 4 consecutive keys per lane -> b64 stores (row = q)
#pragma unroll
                for (int ct = 0; ct < 4; ++ct) {
                    union { p2v h[2]; unsigned long long u; } t;
                    t.h[0] = __builtin_amdgcn_cvt_pkrtz(cc[ct][0], cc[ct][1]);
                    t.h[1] = __builtin_amdgcn_cvt_pkrtz(cc[ct][2], cc[ct][3]);
                    *(unsigned long long*)&sP[(hC * 32 + mtw * 16 + lrow) * PP + ct * 16 + crow4] = t.u;
                }
            } else if (pf) {
                const int stid = (wv << 6) + lane; // 0..511
                float4 kreg[5], vreg[4];
#pragma unroll
                for (int n = 0; n < 5; ++n) {
                    int idx = stid + (n << 9);
                    int h = idx >= 1280;
                    int rem = idx - (h ? 1280 : 0);
                    int e = rem >> 4, d4 = rem & 15;
                    int c = k0n - 5 + e;
                    kreg[n] = make_float4(0.f, 0.f, 0.f, 0.f);
                    if (e < 74 && c >= 0 && c < SS)
                        kreg[n] = K4[((2 * g + h) * SS + c) * 16 + d4];
                }
#pragma unroll
                for (int n = 0; n < 4; ++n) {
                    int idx = stid + (n << 9);
                    int h = idx >> 10, d4 = (idx >> 6) & 15, kk = idx & 63;
                    vreg[n] = V4[((2 * g + h) * SS + k0n + kk) * 16 + d4];
                }
#pragma unroll
                for (int n = 0; n < 5; ++n) {
                    int idx = stid + (n << 9);
                    int h = idx >= 1280;
                    int rem = idx - (h ? 1280 : 0);
                    int e = rem >> 4, d4 = rem & 15;
                    *(unsigned long long*)&sK[nxt][(h * 80 + e) * KP + (d4 << 2)] = pack4h(kreg[n]);
                }
#pragma unroll
                for (int n = 0; n < 4; ++n) {
                    int idx = stid + (n << 9);
                    int h = idx >> 10, d4 = (idx >> 6) & 15, kk = idx & 63;
                    int d = d4 << 2;
                    sVt[nxt][(h * 64 + d + 0) * VP + kk] = (_Float16)vreg[n].x;
                    sVt[nxt][(h * 64 + d + 1) * VP + kk] = (_Float16)vreg[n].y;
                    sVt[nxt][(h * 64 + d + 2) * VP + kk] = (_Float16)vreg[n].z;
                    sVt[nxt][(h * 64 + d + 3) * VP + kk] = (_Float16)vreg[n].w;
                }
            }
            __syncthreads(); // Y: sP/sResc + next buffers published

            // ---- (E) PV: waves 0-7, role (i,j,nh): acc += P_i @ V_j[nh d-half], full K ----
            if (!isConv) {
#pragma unroll
                for (int mt = 0; mt < 2; ++mt)
#pragma unroll
                    for (int r = 0; r < 4; ++r) {
                        float f = sResc[i_pv][mt * 16 + crow4 + r];
                        acc[mt][0][r] *= f;
                        acc[mt][1][r] *= f;
                    }
#pragma unroll
                for (int kh = 0; kh < 2; ++kh)
#pragma unroll
                    for (int mt = 0; mt < 2; ++mt) {
                        h8v a = *(const h8v*)&sP[(i_pv * 32 + mt * 16 + lrow) * PP + (kh << 5) + lk8];
#pragma unroll
                        for (int n2 = 0; n2 < 2; ++n2) {
                            int nt = nh * 2 + n2;
                            h8v b = *(const h8v*)&sVt[cur][(j_pv * 64 + nt * 16 + lrow) * VP + (kh << 5) + lk8];
                            acc[mt][n2] = __builtin_amdgcn_mfma_f32_16x16x32_f16(a, b, acc[mt][n2], 0, 0, 0);
                        }
                    }
            }
            cur = nxt;
            // no barrier: next (B) writes sSf (not touched by E) and reads sK[new cur]
            // (published at Y); PV-phase LDS (sP/sResc/sVt) rewritten only after next X/Y.
        } // it

        if (isConv && (lane >> 4) == 0) sL[hC][mtw * 16 + lrow] = l_run;
        __syncthreads(); // B5: final PV done; sL ready

        // ---- head mixing: 2 barriered stages over i_pv into sO (reuse sK) ----
        float* sO = (float*)&sK[0][0];
#pragma unroll
        for (int st = 0; st < 2; ++st) {
            if (!isConv && i_pv == st) {
#pragma unroll
                for (int mt = 0; mt < 2; ++mt)
#pragma unroll
                    for (int r = 0; r < 4; ++r) {
                        int row = mt * 16 + crow4 + r;
                        float cc2 = mixc / sL[i_pv][row];
#pragma unroll
                        for (int n2 = 0; n2 < 2; ++n2) {
                            int col = (nh * 2 + n2) * 16 + lrow;
                            float val = acc[mt][n2][r] * cc2;
                            if (st == 0) sO[(j_pv * 32 + row) * 68 + col] = val;
                            else         sO[(j_pv * 32 + row) * 68 + col] += val;
                        }
                    }
            }
            __syncthreads();
        }

        // ---- LayerNorm over D + store (1024 items over 768 threads) ----
        {
            const float4* G4 = (const float4*)GAM;
            const float4* B4 = (const float4*)BET;
#pragma unroll
            for (int itl = 0; itl < 2; ++itl) {
                int pidx = tid + itl * 768;
                if (pidx < 1024) {
                    int d4 = pidx & 15, rowj = pidx >> 4; // 0..63
                    int j = rowj >> 5, qq = rowj & 31;
                    float4 o = *(const float4*)&sO[rowj * 68 + (d4 << 2)];
                    float s1 = o.x + o.y + o.z + o.w;
                    float s2 = o.x * o.x + o.y * o.y + o.z * o.z + o.w * o.w;
#pragma unroll
                    for (int off = 1; off < 16; off <<= 1) {
                        s1 += __shfl_xor(s1, off);
                        s2 += __shfl_xor(s2, off);
                    }
                    float mean = s1 * (1.f / 64.f);
                    float var = s2 * (1.f / 64.f) - mean * mean;
                    float rs = rsqrtf(var + 1e-5f);
                    float4 gm = G4[d4], bt = B4[d4];
                    float4 ov;
                    ov.x = (o.x - mean) * rs * gm.x + bt.x;
                    ov.y = (o.y - mean) * rs * gm.y + bt.y;
                    ov.z = (o.z - mean) * rs * gm.z + bt.z;
                    ov.w = (o.w - mean) * rs * gm.w + bt.w;
                    *(float4*)&OUT[(((2 * g + j) * SS + q0 + qq) << 6) + (d4 << 2)] = ov;
                }
            }
        }
    } // ti
}

extern "C" void kernel_launch(void* const* d_in, const int* in_sizes, int n_in,
                              void* d_out, int out_size, void* d_ws, size_t ws_size,
                              hipStream_t stream) {
    const float* q = (const float*)d_in[0];
    const float* k = (const float*)d_in[1];
    const float* v = (const float*)d_in[2];
    const float* cw = (const float*)d_in[3];
    const float* cb = (const float*)d_in[4];
    const float* mix = (const float*)d_in[5];
    const float* gam = (const float*)d_in[6];
    const float* bet = (const float*)d_in[7];
    float* out = (float*)d_out;

    dim3 grid(8 * 32);   // 256 blocks; ~121 KB LDS guarantees 1 block/CU
    dim3 block(768);     // 12 waves = 3 waves/SIMD (VGPR budget 168)
    hipLaunchKernelGGL(mta_v17, grid, block, 0, stream,
                       q, k, v, cw, cb, mix, gam, bet, out);
}

// Round 19
// 101.179 us; speedup vs baseline: 1.0671x; 1.0671x over previous
//
#include <hip/hip_runtime.h>
#include <math.h>

#define SS 2048
#define QP 72   // f16 pitch sQ (48 rows/head)
#define KP 72   // f16 pitch sK (80 rows/head)
#define VP 72   // f16 pitch sVt (64 d-rows/head)
#define SFP 88  // f16 pitch sSf (48 rows/head, 80 cols used)
#define PP 72   // f16 pitch sP (32 q-rows/head, 64 key cols)

typedef __attribute__((ext_vector_type(8))) _Float16 h8v;
typedef __attribute__((ext_vector_type(2))) __fp16 p2v;
typedef __attribute__((ext_vector_type(4))) float f4v;

__device__ __forceinline__ unsigned long long pack4h(float4 v) {
    union { p2v h[2]; unsigned long long u; } t;
    t.h[0] = __builtin_amdgcn_cvt_pkrtz(v.x, v.y);
    t.h[1] = __builtin_amdgcn_cvt_pkrtz(v.z, v.w);
    return t.u;
}

__global__ __launch_bounds__(512, 2)
void mta_v19(const float* __restrict__ Q, const float* __restrict__ K,
             const float* __restrict__ V, const float* __restrict__ CW,
             const float* __restrict__ CB, const float* __restrict__ MIX,
             const float* __restrict__ GAM, const float* __restrict__ BET,
             float* __restrict__ OUT)
{
    __shared__ __align__(16) _Float16 sQ[96 * QP];       // 13824 B
    __shared__ __align__(16) _Float16 sK[2][160 * KP];   // 2 x 23040 B
    __shared__ __align__(16) _Float16 sVt[2][128 * VP];  // 2 x 18432 B
    __shared__ __align__(16) _Float16 sSf[96 * SFP];     // 16896 B
    __shared__ __align__(16) _Float16 sP[64 * PP];       // 9216 B
    __shared__ float sResc[2][32];
    __shared__ float sL[2][32];
    __shared__ float sW2[2][66];
    __shared__ float sB2[2];
    // ~121 KB -> hardware-guaranteed 1 block/CU

    const int tid = threadIdx.x;
    const int g = blockIdx.x & 7;
    const int u = blockIdx.x >> 3;   // 0..31

    const int wv = tid >> 6, lane = tid & 63;
    const int lrow = lane & 15;            // MFMA A/B row, C col
    const int lk8 = (lane >> 4) << 3;      // MFMA contraction offset
    const int crow4 = (lane >> 4) << 2;    // MFMA C row base

    // PV wave role: (i = source head, j = dest head, nh = d-half)
    const int i_pv = wv >> 2, j_pv = (wv >> 1) & 1, nh = wv & 1;
    // conv wave role (waves 0-3): (head, m-tile)
    const int hC = wv >> 1, mtw = wv & 1;

    for (int idx = tid; idx < 132; idx += 512) {
        int h = idx >= 66;
        sW2[h][idx - (h ? 66 : 0)] = CW[(2 * g + h) * 66 + (idx - (h ? 66 : 0))];
    }
    if (tid < 2) sB2[tid] = CB[2 * g + tid];
    const float mixc = MIX[g * 4 + i_pv * 2 + j_pv];
    __syncthreads();

    // ---- T fragments in registers (waves 0-3): tf_i[m=lrow][z=lk8+e] = w[i][z-m] ----
    h8v tf[6];
    float biasC = 0.f;
    if (wv < 4) {
        biasC = sB2[hC];
#pragma unroll
        for (int i = 0; i < 6; ++i)
#pragma unroll
            for (int e = 0; e < 8; ++e) {
                int d = lk8 + e - lrow;
                tf[i][e] = (d >= 0 && d <= 10) ? (_Float16)sW2[hC][i * 11 + d] : (_Float16)0.f;
            }
    }

    const float4* Q4 = (const float4*)Q;
    const float4* K4 = (const float4*)K;
    const float4* V4 = (const float4*)V;

    for (int ti = 0; ti < 2; ++ti) {
        const int tile = ti ? u : (63 - u);   // per-block iteration total constant (33)
        const int q0 = tile << 5;
        __syncthreads(); // P0: prev-ti consumers done before restaging

        // ---- stage extended Q tile (rows q0-2 .. q0+45), f16, pre-scaled by 1/8 ----
        for (int idx = tid; idx < 1536; idx += 512) {
            int h = idx >= 768;
            int rem = idx - (h ? 768 : 0);
            int e = rem >> 4, d4 = rem & 15;
            int r = q0 - 2 + e;
            float4 val = make_float4(0.f, 0.f, 0.f, 0.f);
            if (r >= 0 && r < SS) {
                float4 t = Q4[((2 * g + h) * SS + r) * 16 + d4];
                val = make_float4(t.x * 0.125f, t.y * 0.125f, t.z * 0.125f, t.w * 0.125f);
            }
            *(unsigned long long*)&sQ[(h * 48 + e) * QP + (d4 << 2)] = pack4h(val);
        }
        // ---- direct-stage K/V buffer 0 (k0 = 0) ----
        for (int idx = tid; idx < 2560; idx += 512) {
            int h = idx >= 1280;
            int rem = idx - (h ? 1280 : 0);
            int e = rem >> 4, d4 = rem & 15;
            int c = -5 + e;
            float4 val = make_float4(0.f, 0.f, 0.f, 0.f);
            if (e < 74 && c >= 0 && c < SS) val = K4[((2 * g + h) * SS + c) * 16 + d4];
            *(unsigned long long*)&sK[0][(h * 80 + e) * KP + (d4 << 2)] = pack4h(val);
        }
        for (int idx = tid; idx < 2048; idx += 512) {
            int h = idx >> 10, d4 = (idx >> 6) & 15, kk = idx & 63;
            float4 val = V4[((2 * g + h) * SS + kk) * 16 + d4];
            int d = d4 << 2;
            sVt[0][(h * 64 + d + 0) * VP + kk] = (_Float16)val.x;
            sVt[0][(h * 64 + d + 1) * VP + kk] = (_Float16)val.y;
            sVt[0][(h * 64 + d + 2) * VP + kk] = (_Float16)val.z;
            sVt[0][(h * 64 + d + 3) * VP + kk] = (_Float16)val.w;
        }

        f4v acc[2][2];
#pragma unroll
        for (int mt = 0; mt < 2; ++mt)
#pragma unroll
            for (int n2 = 0; n2 < 2; ++n2) acc[mt][n2] = f4v{0.f, 0.f, 0.f, 0.f};
        float m_run = -INFINITY, l_run = 0.f;
        int cur = 0;

        __syncthreads(); // P1: buffer 0 + Q staged

        const int iters = (tile >> 1) + 1;   // 64 keys per iteration
        for (int it = 0; it < iters; ++it) {
            const int k0 = it << 6;
            const bool pf = (it + 1) < iters;
            const int k0n = (it + 1) << 6;
            const int nxt = cur ^ 1;

            // ---- (B) scores: 2 heads x 3 m-tiles x 5 n-tiles, K=64, masked f16 out ----
#pragma unroll
            for (int jj = 0; jj < 4; ++jj) {
                int job = wv + (jj << 3);
                if (job < 30) {
                    int h = job >= 15;
                    int r15 = job - (h ? 15 : 0);
                    int mt = (r15 >= 10) ? 2 : ((r15 >= 5) ? 1 : 0);
                    int nt = r15 - 5 * mt;
                    const _Float16* ap = &sQ[(h * 48 + mt * 16 + lrow) * QP + lk8];
                    const _Float16* bp = &sK[cur][(h * 80 + nt * 16 + lrow) * KP + lk8];
                    f4v c = f4v{0.f, 0.f, 0.f, 0.f};
                    c = __builtin_amdgcn_mfma_f32_16x16x32_f16(*(const h8v*)ap,
                                                               *(const h8v*)bp, c, 0, 0, 0);
                    c = __builtin_amdgcn_mfma_f32_16x16x32_f16(*(const h8v*)(ap + 32),
                                                               *(const h8v*)(bp + 32), c, 0, 0, 0);
                    int col = nt * 16 + lrow;
                    int cab = k0 - 5 + col;
                    int rbase = mt * 16 + crow4;
#pragma unroll
                    for (int r = 0; r < 4; ++r)
                        sSf[(h * 48 + rbase + r) * SFP + col] =
                            (_Float16)((cab <= q0 - 2 + rbase + r) ? c[r] : 0.f);
                }
            }
            __syncthreads(); // X: sSf published; prev PV done with sP/sResc

            // ---- (C) split: waves 0-3 transposed-conv+softmax; waves 4-7 K/V prefetch ----
            if (wv < 4) {
                // transposed conv: D[m=key][n=q] = mfma(A=tf, B=s_frag); lane holds q=lrow,
                // keys ct*16 + crow4 + r in regs -> softmax is lane-local + 2 shfl.
                f4v cc[4];
                __builtin_amdgcn_s_setprio(1);
#pragma unroll
                for (int ct = 0; ct < 4; ++ct) {
                    f4v c = f4v{biasC, biasC, biasC, biasC};
#pragma unroll
                    for (int i = 0; i < 6; ++i) {
                        h8v b = *(const h8v*)&sSf[(hC * 48 + mtw * 16 + i + lrow) * SFP + ct * 16 + lk8];
                        c = __builtin_amdgcn_mfma_f32_16x16x32_f16(tf[i], b, c, 0, 0, 0);
                    }
                    cc[ct] = c;
                }
                __builtin_amdgcn_s_setprio(0);
                const int qrow = q0 + mtw * 16 + lrow;
                float tm = -INFINITY;
#pragma unroll
                for (int ct = 0; ct < 4; ++ct)
#pragma unroll
                    for (int r = 0; r < 4; ++r) {
                        int ca = k0 + ct * 16 + crow4 + r;
                        float v = cc[ct][r];
                        if (ca > qrow) v = -1e9f;
                        cc[ct][r] = v;
                        tm = fmaxf(tm, v);
                    }
                tm = fmaxf(tm, __shfl_xor(tm, 16));
                tm = fmaxf(tm, __shfl_xor(tm, 32));
                float mnew = fmaxf(m_run, tm);
                float resc = __expf(m_run - mnew); // first iter: exp(-inf)=0
                m_run = mnew;
                float ps = 0.f;
#pragma unroll
                for (int ct = 0; ct < 4; ++ct)
#pragma unroll
                    for (int r = 0; r < 4; ++r) {
                        float p = __expf(cc[ct][r] - mnew);
                        cc[ct][r] = p;
                        ps += p;
                    }
                ps += __shfl_xor(ps, 16);
                ps += __shfl_xor(ps, 32);
                l_run = l_run * resc + ps;
                if ((lane >> 4) == 0) sResc[hC][mtw * 16 + lrow] = resc;
                // P write: 4 consecutive keys per lane -> b64 stores (row = q)
#pragma unroll
                for (int ct = 0; ct < 4; ++ct) {
                    union { p2v h[2]; unsigned long long u; } t;
                    t.h[0] = __builtin_amdgcn_cvt_pkrtz(cc[ct][0], cc[ct][1]);
                    t.h[1] = __builtin_amdgcn_cvt_pkrtz(cc[ct][2], cc[ct][3]);
                    *(unsigned long long*)&sP[(hC * 32 + mtw * 16 + lrow) * PP + ct * 16 + crow4] = t.u;
                }
            } else if (pf) {
                const int stid = ((wv - 4) << 6) + lane; // 0..255
                float4 kreg[10], vreg[8];
#pragma unroll
                for (int n = 0; n < 10; ++n) {
                    int idx = stid + (n << 8);
                    int h = idx >= 1280;
                    int rem = idx - (h ? 1280 : 0);
                    int e = rem >> 4, d4 = rem & 15;
                    int c = k0n - 5 + e;
                    kreg[n] = make_float4(0.f, 0.f, 0.f, 0.f);
                    if (e < 74 && c >= 0 && c < SS)
                        kreg[n] = K4[((2 * g + h) * SS + c) * 16 + d4];
                }
#pragma unroll
                for (int n = 0; n < 8; ++n) {
                    int idx = stid + (n << 8);
                    int h = idx >> 10, d4 = (idx >> 6) & 15, kk = idx & 63;
                    vreg[n] = V4[((2 * g + h) * SS + k0n + kk) * 16 + d4];
                }
#pragma unroll
                for (int n = 0; n < 10; ++n) {
                    int idx = stid + (n << 8);
                    int h = idx >= 1280;
                    int rem = idx - (h ? 1280 : 0);
                    int e = rem >> 4, d4 = rem & 15;
                    *(unsigned long long*)&sK[nxt][(h * 80 + e) * KP + (d4 << 2)] = pack4h(kreg[n]);
                }
#pragma unroll
                for (int n = 0; n < 8; ++n) {
                    int idx = stid + (n << 8);
                    int h = idx >> 10, d4 = (idx >> 6) & 15, kk = idx & 63;
                    int d = d4 << 2;
                    sVt[nxt][(h * 64 + d + 0) * VP + kk] = (_Float16)vreg[n].x;
                    sVt[nxt][(h * 64 + d + 1) * VP + kk] = (_Float16)vreg[n].y;
                    sVt[nxt][(h * 64 + d + 2) * VP + kk] = (_Float16)vreg[n].z;
                    sVt[nxt][(h * 64 + d + 3) * VP + kk] = (_Float16)vreg[n].w;
                }
            }
            __syncthreads(); // Y: sP/sResc + next buffers published

            // ---- (E) PV: wave (i,j,nh): acc += P_i @ V_j[nh d-half], full K ----
            {
#pragma unroll
                for (int mt = 0; mt < 2; ++mt)
#pragma unroll
                    for (int r = 0; r < 4; ++r) {
                        float f = sResc[i_pv][mt * 16 + crow4 + r];
                        acc[mt][0][r] *= f;
                        acc[mt][1][r] *= f;
                    }
#pragma unroll
                for (int kh = 0; kh < 2; ++kh)
#pragma unroll
                    for (int mt = 0; mt < 2; ++mt) {
                        h8v a = *(const h8v*)&sP[(i_pv * 32 + mt * 16 + lrow) * PP + (kh << 5) + lk8];
#pragma unroll
                        for (int n2 = 0; n2 < 2; ++n2) {
                            int nt = nh * 2 + n2;
                            h8v b = *(const h8v*)&sVt[cur][(j_pv * 64 + nt * 16 + lrow) * VP + (kh << 5) + lk8];
                            acc[mt][n2] = __builtin_amdgcn_mfma_f32_16x16x32_f16(a, b, acc[mt][n2], 0, 0, 0);
                        }
                    }
            }
            cur = nxt;
            // no barrier: next (B) writes sSf (not touched by E) and reads sK[new cur]
        } // it

        if (wv < 4 && (lane >> 4) == 0) sL[hC][mtw * 16 + lrow] = l_run;
        __syncthreads(); // B5: final PV done; sL ready

        // ---- head mixing: 2 barriered stages over i_pv into sO (reuse sK) ----
        float* sO = (float*)&sK[0][0];
#pragma unroll
        for (int st = 0; st < 2; ++st) {
            if (i_pv == st) {
#pragma unroll
                for (int mt = 0; mt < 2; ++mt)
#pragma unroll
                    for (int r = 0; r < 4; ++r) {
                        int row = mt * 16 + crow4 + r;
                        float cc2 = mixc / sL[i_pv][row];
#pragma unroll
                        for (int n2 = 0; n2 < 2; ++n2) {
                            int col = (nh * 2 + n2) * 16 + lrow;
                            float val = acc[mt][n2][r] * cc2;
                            if (st == 0) sO[(j_pv * 32 + row) * 68 + col] = val;
                            else         sO[(j_pv * 32 + row) * 68 + col] += val;
                        }
                    }
            }
            __syncthreads();
        }

        // ---- LayerNorm over D + store (2 items/thread) ----
        {
            const float4* G4 = (const float4*)GAM;
            const float4* B4 = (const float4*)BET;
#pragma unroll
            for (int itl = 0; itl < 2; ++itl) {
                int pidx = tid + (itl << 9);
                int d4 = pidx & 15, rowj = pidx >> 4; // 0..63
                int j = rowj >> 5, qq = rowj & 31;
                float4 o = *(const float4*)&sO[rowj * 68 + (d4 << 2)];
                float s1 = o.x + o.y + o.z + o.w;
                float s2 = o.x * o.x + o.y * o.y + o.z * o.z + o.w * o.w;
#pragma unroll
                for (int off = 1; off < 16; off <<= 1) {
                    s1 += __shfl_xor(s1, off);
                    s2 += __shfl_xor(s2, off);
                }
                float mean = s1 * (1.f / 64.f);
                float var = s2 * (1.f / 64.f) - mean * mean;
                float rs = rsqrtf(var + 1e-5f);
                float4 gm = G4[d4], bt = B4[d4];
                float4 ov;
                ov.x = (o.x - mean) * rs * gm.x + bt.x;
                ov.y = (o.y - mean) * rs * gm.y + bt.y;
                ov.z = (o.z - mean) * rs * gm.z + bt.z;
                ov.w = (o.w - mean) * rs * gm.w + bt.w;
                *(float4*)&OUT[(((2 * g + j) * SS + q0 + qq) << 6) + (d4 << 2)] = ov;
            }
        }
    } // ti
}

extern "C" void kernel_launch(void* const* d_in, const int* in_sizes, int n_in,
                              void* d_out, int out_size, void* d_ws, size_t ws_size,
                              hipStream_t stream) {
    const float* q = (const float*)d_in[0];
    const float* k = (const float*)d_in[1];
    const float* v = (const float*)d_in[2];
    const float* cw = (const float*)d_in[3];
    const float* cb = (const float*)d_in[4];
    const float* mix = (const float*)d_in[5];
    const float* gam = (const float*)d_in[6];
    const float* bet = (const float*)d_in[7];
    float* out = (float*)d_out;

    dim3 grid(8 * 32);   // 256 blocks; ~121 KB LDS guarantees 1 block/CU
    dim3 block(512);     // 8 waves = 2 waves/SIMD
    hipLaunchKernelGGL(mta_v19, grid, block, 0, stream,
                       q, k, v, cw, cb, mix, gam, bet, out);
}